// Round 15
// baseline (211.953 us; speedup 1.0000x reference)
//
#include <hip/hip_runtime.h>
#include <hip/hip_bf16.h>
#include <stdint.h>

// N=4096, D=1024, H=512, C=21. All inputs f32; d_out f32:
//   [labels 4096][cls_prob 4096*21][bbox 4096*84]
// Factored GCN: A = diag(r) X X^T diag(r) - I  (r_i = 1/||x_i||)
//   => A@S = diag(r)*(X @ (S^T R X)^T) - S.
// R15 (on R14, 206.1us): BK 64->128 via XOR-swizzled LDS (64KB exact, no pad)
//   — halves K-loop barrier count again (K=1024: 8 iters, 32 MFMAs/wave per
//   barrier). Swizzle: phys = row*128 + ((g ^ (row&7))*8), conflict-free to
//   2-way. All else identical to R14. 14 dispatches.

typedef __attribute__((ext_vector_type(8))) short short8;
typedef __attribute__((ext_vector_type(4))) float floatx4;

#define BK 128

__device__ __forceinline__ unsigned short bfbits(float f) {
  union { float f; unsigned int i; } u; u.f = f;
  unsigned int r = u.i + 0x7fffu + ((u.i >> 16) & 1);  // RNE
  return (unsigned short)(r >> 16);
}

// ---------------- GEMM 64x64 tile: acc = P[M,KC@z] @ Q[N,KC@z]^T ----------------
// 4 waves, wave tile 32x32 (acc 2x2). Ping-pong XOR-swizzled LDS, global
// prefetch 1 iter ahead. KC must be a multiple of 128.
// MODE 0: f32 partials part[z*MN + row*N + col]
// MODE 1: ST[row*4096+col] = bf16(v)
// MODE 2: h[row*512+col] = bf16(relu(rinorm[row]*v - ST[col*4096+row] + bias[col]))
// MODE 3: heads: bx=0 -> bbox cols 0..63; bx=1 -> bbox 64..83 + softmax(cls 84..104)
template <int MODE>
__global__ __launch_bounds__(256) void gemm64(
    const __hip_bfloat16* __restrict__ P, const __hip_bfloat16* __restrict__ Q,
    int KC, int ld, int N, float* __restrict__ part,
    const float* __restrict__ rinorm, const __hip_bfloat16* __restrict__ ST,
    const float* __restrict__ bias, __hip_bfloat16* __restrict__ outb,
    float* __restrict__ outf, float* __restrict__ cls, const float* __restrict__ bias2) {
  __shared__ short As[2][64 * 128];  // 16 KB each; total A+B dbuf = 64 KB exact
  __shared__ short Bs[2][64 * 128];
  const int tid = threadIdx.x;
  const int w = tid >> 6, lane = tid & 63;
  const size_t m0 = (size_t)blockIdx.y * 64, n0 = (size_t)blockIdx.x * 64;
  const int z = blockIdx.z;

  // staging: 64 rows x 128 shorts; 4 threads/row, 4 groups (short8) each
  const int srow = tid >> 2, sg0 = (tid & 3) * 4, s7 = srow & 7;
  const short* gA = (const short*)P + (m0 + srow) * (size_t)ld + (size_t)z * KC + sg0 * 8;
  const short* gB = (const short*)Q + (n0 + srow) * (size_t)ld + (size_t)z * KC + sg0 * 8;
  int soff[4];
#pragma unroll
  for (int k = 0; k < 4; ++k) soff[k] = srow * 128 + (((sg0 + k) ^ s7) * 8);

  const int wm = (w >> 1) * 32, wn = (w & 1) * 32;  // wave tile 32x32
  const int lr = lane & 15, hi = lane >> 4, r7 = lr & 7;

  floatx4 acc[2][2];
#pragma unroll
  for (int i = 0; i < 2; ++i)
#pragma unroll
    for (int j = 0; j < 2; ++j) acc[i][j] = (floatx4){0.f, 0.f, 0.f, 0.f};

  const int nIter = KC / BK;
  short8 ra[4], rb[4];
#pragma unroll
  for (int k = 0; k < 4; ++k) {
    ra[k] = *(const short8*)(gA + k * 8);
    rb[k] = *(const short8*)(gB + k * 8);
  }
#pragma unroll
  for (int k = 0; k < 4; ++k) {
    *(short8*)&As[0][soff[k]] = ra[k];
    *(short8*)&Bs[0][soff[k]] = rb[k];
  }
  if (nIter > 1) {
#pragma unroll
    for (int k = 0; k < 4; ++k) {
      ra[k] = *(const short8*)(gA + BK + k * 8);
      rb[k] = *(const short8*)(gB + BK + k * 8);
    }
  }
  __syncthreads();

  for (int it = 0; it < nIter; ++it) {
    const int cur = it & 1;
    if (it + 1 < nIter) {
      // store chunk it+1 into the other buffer (consumed in prev iter, barrier passed)
#pragma unroll
      for (int k = 0; k < 4; ++k) {
        *(short8*)&As[cur ^ 1][soff[k]] = ra[k];
        *(short8*)&Bs[cur ^ 1][soff[k]] = rb[k];
      }
      if (it + 2 < nIter) {
        const int off = (it + 2) * BK;
#pragma unroll
        for (int k = 0; k < 4; ++k) {
          ra[k] = *(const short8*)(gA + off + k * 8);
          rb[k] = *(const short8*)(gB + off + k * 8);
        }
      }
    }
#pragma unroll
    for (int ks = 0; ks < 4; ++ks) {  // ascending K: accumulation order identical
      short8 av[2], bv[2];
      const int gph = ((ks * 4 + hi) ^ r7) * 8;  // swizzled group offset (row&7 == lr&7)
#pragma unroll
      for (int t = 0; t < 2; ++t) {
        av[t] = *(const short8*)&As[cur][(wm + t * 16 + lr) * 128 + gph];
        bv[t] = *(const short8*)&Bs[cur][(wn + t * 16 + lr) * 128 + gph];
      }
#pragma unroll
      for (int i = 0; i < 2; ++i)
#pragma unroll
        for (int j = 0; j < 2; ++j)
          acc[i][j] = __builtin_amdgcn_mfma_f32_16x16x32_bf16(av[i], bv[j], acc[i][j], 0, 0, 0);
    }
    __syncthreads();
  }

  const size_t MN = (size_t)(gridDim.y * 64) * (size_t)N;
  float* cp = part + (size_t)z * MN;
  float* lg = (float*)&As[0][0];  // MODE 3: 64x22 f32 logit stage (LDS dead after loop)
  const int rb4 = hi * 4;
#pragma unroll
  for (int i = 0; i < 2; ++i)
#pragma unroll
    for (int j = 0; j < 2; ++j)
#pragma unroll
      for (int r = 0; r < 4; ++r) {
        int row = (int)m0 + wm + i * 16 + rb4 + r;
        int col = (int)n0 + wn + j * 16 + lr;
        float v = acc[i][j][r];
        if (MODE == 0) {
          cp[(size_t)row * N + col] = v;
        } else if (MODE == 1) {
          outb[(size_t)row * 4096 + col] = __float2bfloat16(v);  // ST coalesced
        } else if (MODE == 2) {
          v = rinorm[row] * v - __bfloat162float(ST[(size_t)col * 4096 + row]) + bias[col];
          outb[(size_t)row * 512 + col] = __float2bfloat16(fmaxf(v, 0.f));
        } else {
          if (blockIdx.x == 0) {
            outf[(size_t)row * 84 + col] = v + bias[col];  // bbox cols 0..63
          } else {
            int lrow = wm + i * 16 + rb4 + r;  // 0..63
            if (col < 84) outf[(size_t)row * 84 + col] = v + bias[col];  // 64..83
            else if (col < 105) lg[lrow * 22 + (col - 84)] = v + bias2[col - 84];
          }
        }
      }
  if (MODE == 3) {
    __syncthreads();
    if (blockIdx.x == 1 && tid < 64) {
      const float* Lr = &lg[tid * 22];
      float m = Lr[0];
#pragma unroll
      for (int k = 1; k < 21; ++k) m = fmaxf(m, Lr[k]);
      float s = 0.f;
      float e[21];
#pragma unroll
      for (int k = 0; k < 21; ++k) { e[k] = expf(Lr[k] - m); s += e[k]; }
      float inv = 1.f / s;
      float* dst = &cls[(m0 + tid) * 21];
#pragma unroll
      for (int k = 0; k < 21; ++k) dst[k] = e[k] * inv;
    }
  }
}

// ---------------- reduces ----------------
// red0: out[i] = bf16(sum_{s<ns} part[s*n + i]); float4 lanes
__global__ void k_red0(const float* __restrict__ part, __hip_bfloat16* __restrict__ out,
                       int n, int ns) {
  int i = (blockIdx.x * 256 + threadIdx.x) * 4;
  if (i >= n) return;
  float4 v = *(const float4*)(part + i);
  for (int s = 1; s < ns; ++s) {
    float4 q = *(const float4*)(part + (size_t)s * n + i);
    v.x += q.x; v.y += q.y; v.z += q.z; v.w += q.w;
  }
  out[i] = __float2bfloat16(v.x);
  out[i + 1] = __float2bfloat16(v.y);
  out[i + 2] = __float2bfloat16(v.z);
  out[i + 3] = __float2bfloat16(v.w);
}

// ---------------- D1: nf + adj(+hook0) merged ----------------
__global__ void k_nf_adj(const float* __restrict__ X, __hip_bfloat16* __restrict__ Xb,
                         float* __restrict__ rinorm, const float4* __restrict__ rois,
                         unsigned long long* __restrict__ adj, int* __restrict__ labels) {
  int blk = blockIdx.x, tid = threadIdx.x;
  int lane = tid & 63;
  if (blk < 1024) {  // nf: rinorm + bf16 convert
    int wave = (blk * 256 + tid) >> 6;
    const float4* row = (const float4*)(X + (size_t)wave * 1024);
    uint2* orow = (uint2*)((short*)Xb + (size_t)wave * 1024);
    float s = 0.f;
#pragma unroll
    for (int it = 0; it < 4; ++it) {
      float4 p = row[lane + it * 64];
      s += p.x * p.x + p.y * p.y + p.z * p.z + p.w * p.w;
      uint2 q;
      q.x = (unsigned int)bfbits(p.x) | ((unsigned int)bfbits(p.y) << 16);
      q.y = (unsigned int)bfbits(p.z) | ((unsigned int)bfbits(p.w) << 16);
      orow[lane + it * 64] = q;
    }
    for (int o = 32; o; o >>= 1) s += __shfl_down(s, o);
    if (lane == 0) rinorm[wave] = 1.f / fmaxf(sqrtf(s), 1e-6f);
  } else {  // adj build + fused hook0
    int node = ((blk - 1024) * 256 + tid) >> 6;
    float4 bi = rois[node];
    unsigned long long myword = 0;
    int mn = node;
    for (int w = 0; w < 64; ++w) {
      int j = w * 64 + lane;
      float4 bj = rois[j];
      float iw = fminf(bi.z, bj.z) - fmaxf(bi.x, bj.x) + 1.0f;
      float ih = fminf(bi.w, bj.w) - fmaxf(bi.y, bj.y) + 1.0f;
      bool ov = (iw > 0.f) && (ih > 0.f) && (j != node);
      unsigned long long msk = __ballot(ov);
      if (lane == w) myword = msk;
      if (msk) mn = min(mn, w * 64 + (int)__builtin_ctzll(msk));
    }
    adj[(size_t)node * 64 + lane] = myword;
    if (lane == 0) labels[node] = mn;
  }
}

// merged prep: [0,4096) XRT transpose (Xb*rinorm), [4096,4608) Wg1T,
//              [4608,4864) Wg2T, [4864,5120) WcatT
__global__ void k_prep(const __hip_bfloat16* __restrict__ Xb, const float* __restrict__ rinorm,
                       const float* __restrict__ Wg1, const float* __restrict__ Wg2,
                       const float* __restrict__ Wb, const float* __restrict__ Wc,
                       __hip_bfloat16* __restrict__ XRT, __hip_bfloat16* __restrict__ Wg1T,
                       __hip_bfloat16* __restrict__ Wg2T, __hip_bfloat16* __restrict__ WcatT) {
  __shared__ float s[32][33];
  const int tid = threadIdx.x;
  const int tx = tid & 31, ty = tid >> 5;  // (32,8)
  int blk = blockIdx.x;
  if (blk < 4096) {
    int c0 = (blk & 31) * 32, r0 = (blk >> 5) * 32;
#pragma unroll
    for (int k = 0; k < 4; ++k) {
      int r = r0 + ty + k * 8;
      s[ty + k * 8][tx] = __bfloat162float(Xb[(size_t)r * 1024 + c0 + tx]) * rinorm[r];
    }
    __syncthreads();
#pragma unroll
    for (int k = 0; k < 4; ++k)
      XRT[(size_t)(c0 + ty + k * 8) * 4096 + r0 + tx] = __float2bfloat16(s[tx][ty + k * 8]);
  } else if (blk < 4608) {
    int l = blk - 4096;
    int c0 = (l & 15) * 32, r0 = (l >> 4) * 32;
#pragma unroll
    for (int k = 0; k < 4; ++k)
      s[ty + k * 8][tx] = Wg1[(size_t)(r0 + ty + k * 8) * 512 + c0 + tx];
    __syncthreads();
#pragma unroll
    for (int k = 0; k < 4; ++k)
      Wg1T[(size_t)(c0 + ty + k * 8) * 1024 + r0 + tx] = __float2bfloat16(s[tx][ty + k * 8]);
  } else if (blk < 4864) {
    int l = blk - 4608;
    int c0 = (l & 15) * 32, r0 = (l >> 4) * 32;
#pragma unroll
    for (int k = 0; k < 4; ++k)
      s[ty + k * 8][tx] = Wg2[(size_t)(r0 + ty + k * 8) * 512 + c0 + tx];
    __syncthreads();
#pragma unroll
    for (int k = 0; k < 4; ++k)
      Wg2T[(size_t)(c0 + ty + k * 8) * 512 + r0 + tx] = __float2bfloat16(s[tx][ty + k * 8]);
  } else {
    int idx = (blk - 4864) * 256 + tid;
    int r = idx >> 9, k = idx & 511;
    float v = 0.f;
    if (r < 84) v = Wb[(size_t)k * 84 + r];
    else if (r < 105) v = Wc[(size_t)k * 21 + (r - 84)];
    WcatT[idx] = __float2bfloat16(v);
  }
}

// ---------------- connected components ----------------
__global__ void k_minprop(const unsigned long long* __restrict__ adj, int* __restrict__ labels) {
  int wave = (blockIdx.x * 256 + threadIdx.x) >> 6;
  int lane = threadIdx.x & 63;
  unsigned long long w = adj[(size_t)wave * 64 + lane];
  int m = 0x7fffffff;
  while (w) {
    int b = __builtin_ctzll(w);
    w &= w - 1;
    m = min(m, labels[lane * 64 + b]);
  }
  for (int o = 32; o; o >>= 1) m = min(m, __shfl_down(m, o));
  if (lane == 0 && m < labels[wave]) atomicMin(&labels[wave], m);
}

__global__ void k_jump(int* __restrict__ labels, float* __restrict__ outL) {
  __shared__ int a[4096];
  __shared__ int b[4096];
  int t = threadIdx.x;
  for (int i = t; i < 4096; i += 1024) a[i] = labels[i];
  __syncthreads();
  int* src = a;
  int* dst = b;
  for (int it = 0; it < 12; ++it) {  // 2^12 >= 4096
    for (int i = t; i < 4096; i += 1024) dst[i] = src[src[i]];
    __syncthreads();
    int* tp = src; src = dst; dst = tp;
  }
  for (int i = t; i < 4096; i += 1024) outL[i] = (float)src[i];
}

// ---------------- launch ----------------
extern "C" void kernel_launch(void* const* d_in, const int* in_sizes, int n_in,
                              void* d_out, int out_size, void* d_ws, size_t ws_size,
                              hipStream_t stream) {
  const float* rois = (const float*)d_in[0];
  const float* X    = (const float*)d_in[1];
  const float* Wg1  = (const float*)d_in[2];
  const float* bg1  = (const float*)d_in[3];
  const float* Wg2  = (const float*)d_in[4];
  const float* bg2  = (const float*)d_in[5];
  const float* Wb   = (const float*)d_in[6];
  const float* bb   = (const float*)d_in[7];
  const float* Wc   = (const float*)d_in[8];
  const float* bc   = (const float*)d_in[9];

  float* out        = (float*)d_out;
  float* out_labels = out;
  float* out_cls    = out + 4096;
  float* out_bbox   = out + 4096 + 4096 * 21;

  char* p = (char*)d_ws;
  auto carve = [&](size_t bytes) { char* r = p; p += (bytes + 255) & ~(size_t)255; return r; };
  int* labels           = (int*)carve(4096ull * 4);
  float* rinorm         = (float*)carve(4096ull * 4);
  __hip_bfloat16* WcatT = (__hip_bfloat16*)carve(128ull * 512 * 2);
  __hip_bfloat16* Wg2T  = (__hip_bfloat16*)carve(512ull * 512 * 2);
  __hip_bfloat16* Wg1T  = (__hip_bfloat16*)carve(512ull * 1024 * 2);
  __hip_bfloat16* T2T   = (__hip_bfloat16*)carve(512ull * 1024 * 2);
  __hip_bfloat16* h     = (__hip_bfloat16*)carve(4096ull * 512 * 2);
  __hip_bfloat16* ST    = (__hip_bfloat16*)carve(512ull * 4096 * 2);
  __hip_bfloat16* Xb    = (__hip_bfloat16*)carve(4096ull * 1024 * 2);
  __hip_bfloat16* XRT   = (__hip_bfloat16*)carve(1024ull * 4096 * 2);
  unsigned long long* adj = (unsigned long long*)carve(4096ull * 64 * 8);
  float* part           = (float*)carve(16ull * 1024 * 1024);

  // D1: nf + adj(+hook0)
  k_nf_adj<<<2048, 256, 0, stream>>>(X, Xb, rinorm, (const float4*)rois, adj, labels);
  // D2: prep (transposes + Wcat)
  k_prep<<<5120, 256, 0, stream>>>(Xb, rinorm, Wg1, Wg2, Wb, Wc, XRT, Wg1T, Wg2T, WcatT);
  // CC: 2 atomic hooks, final compress
  for (int r = 0; r < 2; ++r) k_minprop<<<1024, 256, 0, stream>>>(adj, labels);
  k_jump<<<1, 1024, 0, stream>>>(labels, out_labels);

  // ---- layer 1 ----
  gemm64<1><<<dim3(64, 8), 256, 0, stream>>>(Wg1T, Xb, 1024, 1024, 4096, part,
                                             nullptr, nullptr, nullptr, ST,
                                             nullptr, nullptr, nullptr);
  gemm64<0><<<dim3(16, 8, 4), 256, 0, stream>>>(ST, XRT, 1024, 4096, 1024, part,
                                                nullptr, nullptr, nullptr, nullptr,
                                                nullptr, nullptr, nullptr);
  k_red0<<<512, 256, 0, stream>>>(part, T2T, 512 * 1024, 4);
  gemm64<2><<<dim3(8, 64), 256, 0, stream>>>(Xb, T2T, 1024, 1024, 512, part,
                                             rinorm, ST, bg1, h,
                                             nullptr, nullptr, nullptr);
  // ---- layer 2 ----
  gemm64<1><<<dim3(64, 8), 256, 0, stream>>>(Wg2T, h, 512, 512, 4096, part,
                                             nullptr, nullptr, nullptr, ST,
                                             nullptr, nullptr, nullptr);
  gemm64<0><<<dim3(16, 8, 4), 256, 0, stream>>>(ST, XRT, 1024, 4096, 1024, part,
                                                nullptr, nullptr, nullptr, nullptr,
                                                nullptr, nullptr, nullptr);
  k_red0<<<512, 256, 0, stream>>>(part, T2T, 512 * 1024, 4);
  gemm64<2><<<dim3(8, 64), 256, 0, stream>>>(Xb, T2T, 1024, 1024, 512, part,
                                             rinorm, ST, bg2, h,
                                             nullptr, nullptr, nullptr);
  // ---- heads: unsplit K=512, direct bbox + fused softmax ----
  gemm64<3><<<dim3(2, 64), 256, 0, stream>>>(h, WcatT, 512, 512, 128, part,
                                             nullptr, nullptr, bb, nullptr,
                                             out_bbox, out_cls, bc);
}

// Round 16
// 205.795 us; speedup vs baseline: 1.0299x; 1.0299x over previous
//
#include <hip/hip_runtime.h>
#include <hip/hip_bf16.h>
#include <stdint.h>

// N=4096, D=1024, H=512, C=21. All inputs f32; d_out f32:
//   [labels 4096][cls_prob 4096*21][bbox 4096*84]
// Factored GCN: A = diag(r) X X^T diag(r) - I  (r_i = 1/||x_i||)
//   => A@S = diag(r)*(X @ (S^T R X)^T) - S.
// R16 = exact revert to R14 (206.1us, measured best). BK=64 / LSTR=72 is the
// optimum: R15's BK=128+swizzle regressed (+6us — swizzle VALU in hot loop,
// 2x prefetch regs, shorter overlap window). 14 dispatches.

typedef __attribute__((ext_vector_type(8))) short short8;
typedef __attribute__((ext_vector_type(4))) float floatx4;

#define BK 64
#define LSTR 72  // LDS row stride in shorts; b128 reads at this stride <=2-way aliased

__device__ __forceinline__ unsigned short bfbits(float f) {
  union { float f; unsigned int i; } u; u.f = f;
  unsigned int r = u.i + 0x7fffu + ((u.i >> 16) & 1);  // RNE
  return (unsigned short)(r >> 16);
}

// ---------------- GEMM 64x64 tile: acc = P[M,KC@z] @ Q[N,KC@z]^T ----------------
// 4 waves, wave tile 32x32 (acc 2x2). Ping-pong LDS, global prefetch 1 iter ahead.
// MODE 0: f32 partials part[z*MN + row*N + col]
// MODE 1: ST[row*4096+col] = bf16(v)
// MODE 2: h[row*512+col] = bf16(relu(rinorm[row]*v - ST[col*4096+row] + bias[col]))
// MODE 3: heads: bx=0 -> bbox cols 0..63; bx=1 -> bbox 64..83 + softmax(cls 84..104)
template <int MODE>
__global__ __launch_bounds__(256) void gemm64(
    const __hip_bfloat16* __restrict__ P, const __hip_bfloat16* __restrict__ Q,
    int KC, int ld, int N, float* __restrict__ part,
    const float* __restrict__ rinorm, const __hip_bfloat16* __restrict__ ST,
    const float* __restrict__ bias, __hip_bfloat16* __restrict__ outb,
    float* __restrict__ outf, float* __restrict__ cls, const float* __restrict__ bias2) {
  __shared__ short As[2][64 * LSTR];
  __shared__ short Bs[2][64 * LSTR];
  const int tid = threadIdx.x;
  const int w = tid >> 6, lane = tid & 63;
  const size_t m0 = (size_t)blockIdx.y * 64, n0 = (size_t)blockIdx.x * 64;
  const int z = blockIdx.z;

  // staging: 64 rows x 64 shorts; 4 threads/row, 16 shorts (2x short8) each
  const int srow = tid >> 2, skoff = (tid & 3) * 16;
  const short* gA = (const short*)P + (m0 + srow) * (size_t)ld + (size_t)z * KC + skoff;
  const short* gB = (const short*)Q + (n0 + srow) * (size_t)ld + (size_t)z * KC + skoff;
  const int soff = srow * LSTR + skoff;

  const int wm = (w >> 1) * 32, wn = (w & 1) * 32;  // wave tile 32x32
  const int lr = lane & 15, ko = (lane >> 4) * 8;

  floatx4 acc[2][2];
#pragma unroll
  for (int i = 0; i < 2; ++i)
#pragma unroll
    for (int j = 0; j < 2; ++j) acc[i][j] = (floatx4){0.f, 0.f, 0.f, 0.f};

  const int nIter = KC / BK;
  short8 ra0 = *(const short8*)gA;
  short8 ra1 = *(const short8*)(gA + 8);
  short8 rb0 = *(const short8*)gB;
  short8 rb1 = *(const short8*)(gB + 8);
  *(short8*)&As[0][soff] = ra0;
  *(short8*)&As[0][soff + 8] = ra1;
  *(short8*)&Bs[0][soff] = rb0;
  *(short8*)&Bs[0][soff + 8] = rb1;
  if (nIter > 1) {
    ra0 = *(const short8*)(gA + BK);
    ra1 = *(const short8*)(gA + BK + 8);
    rb0 = *(const short8*)(gB + BK);
    rb1 = *(const short8*)(gB + BK + 8);
  }
  __syncthreads();

  for (int it = 0; it < nIter; ++it) {
    const int cur = it & 1;
    short8 av[2][2], bv[2][2];  // [k-step][tile]
#pragma unroll
    for (int ks = 0; ks < 2; ++ks)
#pragma unroll
      for (int t = 0; t < 2; ++t) {
        av[ks][t] = *(const short8*)&As[cur][(wm + t * 16 + lr) * LSTR + ks * 32 + ko];
        bv[ks][t] = *(const short8*)&Bs[cur][(wn + t * 16 + lr) * LSTR + ks * 32 + ko];
      }
    if (it + 1 < nIter) {
      *(short8*)&As[cur ^ 1][soff] = ra0;
      *(short8*)&As[cur ^ 1][soff + 8] = ra1;
      *(short8*)&Bs[cur ^ 1][soff] = rb0;
      *(short8*)&Bs[cur ^ 1][soff + 8] = rb1;
      if (it + 2 < nIter) {
        const int off = (it + 2) * BK;
        ra0 = *(const short8*)(gA + off);
        ra1 = *(const short8*)(gA + off + 8);
        rb0 = *(const short8*)(gB + off);
        rb1 = *(const short8*)(gB + off + 8);
      }
    }
#pragma unroll
    for (int ks = 0; ks < 2; ++ks)  // ascending K keeps accumulation order identical
#pragma unroll
      for (int i = 0; i < 2; ++i)
#pragma unroll
        for (int j = 0; j < 2; ++j)
          acc[i][j] = __builtin_amdgcn_mfma_f32_16x16x32_bf16(av[ks][i], bv[ks][j], acc[i][j], 0, 0, 0);
    __syncthreads();
  }

  const size_t MN = (size_t)(gridDim.y * 64) * (size_t)N;
  float* cp = part + (size_t)z * MN;
  float* lg = (float*)&As[0][0];  // MODE 3: 64x22 f32 logit stage (LDS dead after loop)
  const int rb4 = (lane >> 4) * 4;
#pragma unroll
  for (int i = 0; i < 2; ++i)
#pragma unroll
    for (int j = 0; j < 2; ++j)
#pragma unroll
      for (int r = 0; r < 4; ++r) {
        int row = (int)m0 + wm + i * 16 + rb4 + r;
        int col = (int)n0 + wn + j * 16 + lr;
        float v = acc[i][j][r];
        if (MODE == 0) {
          cp[(size_t)row * N + col] = v;
        } else if (MODE == 1) {
          outb[(size_t)row * 4096 + col] = __float2bfloat16(v);  // ST coalesced
        } else if (MODE == 2) {
          v = rinorm[row] * v - __bfloat162float(ST[(size_t)col * 4096 + row]) + bias[col];
          outb[(size_t)row * 512 + col] = __float2bfloat16(fmaxf(v, 0.f));
        } else {
          if (blockIdx.x == 0) {
            outf[(size_t)row * 84 + col] = v + bias[col];  // bbox cols 0..63
          } else {
            int lrow = wm + i * 16 + rb4 + r;  // 0..63
            if (col < 84) outf[(size_t)row * 84 + col] = v + bias[col];  // 64..83
            else if (col < 105) lg[lrow * 22 + (col - 84)] = v + bias2[col - 84];
          }
        }
      }
  if (MODE == 3) {
    __syncthreads();
    if (blockIdx.x == 1 && tid < 64) {
      const float* Lr = &lg[tid * 22];
      float m = Lr[0];
#pragma unroll
      for (int k = 1; k < 21; ++k) m = fmaxf(m, Lr[k]);
      float s = 0.f;
      float e[21];
#pragma unroll
      for (int k = 0; k < 21; ++k) { e[k] = expf(Lr[k] - m); s += e[k]; }
      float inv = 1.f / s;
      float* dst = &cls[(m0 + tid) * 21];
#pragma unroll
      for (int k = 0; k < 21; ++k) dst[k] = e[k] * inv;
    }
  }
}

// ---------------- reduces ----------------
// red0: out[i] = bf16(sum_{s<ns} part[s*n + i]); float4 lanes
__global__ void k_red0(const float* __restrict__ part, __hip_bfloat16* __restrict__ out,
                       int n, int ns) {
  int i = (blockIdx.x * 256 + threadIdx.x) * 4;
  if (i >= n) return;
  float4 v = *(const float4*)(part + i);
  for (int s = 1; s < ns; ++s) {
    float4 q = *(const float4*)(part + (size_t)s * n + i);
    v.x += q.x; v.y += q.y; v.z += q.z; v.w += q.w;
  }
  out[i] = __float2bfloat16(v.x);
  out[i + 1] = __float2bfloat16(v.y);
  out[i + 2] = __float2bfloat16(v.z);
  out[i + 3] = __float2bfloat16(v.w);
}

// ---------------- D1: nf + adj(+hook0) merged ----------------
__global__ void k_nf_adj(const float* __restrict__ X, __hip_bfloat16* __restrict__ Xb,
                         float* __restrict__ rinorm, const float4* __restrict__ rois,
                         unsigned long long* __restrict__ adj, int* __restrict__ labels) {
  int blk = blockIdx.x, tid = threadIdx.x;
  int lane = tid & 63;
  if (blk < 1024) {  // nf: rinorm + bf16 convert
    int wave = (blk * 256 + tid) >> 6;
    const float4* row = (const float4*)(X + (size_t)wave * 1024);
    uint2* orow = (uint2*)((short*)Xb + (size_t)wave * 1024);
    float s = 0.f;
#pragma unroll
    for (int it = 0; it < 4; ++it) {
      float4 p = row[lane + it * 64];
      s += p.x * p.x + p.y * p.y + p.z * p.z + p.w * p.w;
      uint2 q;
      q.x = (unsigned int)bfbits(p.x) | ((unsigned int)bfbits(p.y) << 16);
      q.y = (unsigned int)bfbits(p.z) | ((unsigned int)bfbits(p.w) << 16);
      orow[lane + it * 64] = q;
    }
    for (int o = 32; o; o >>= 1) s += __shfl_down(s, o);
    if (lane == 0) rinorm[wave] = 1.f / fmaxf(sqrtf(s), 1e-6f);
  } else {  // adj build + fused hook0
    int node = ((blk - 1024) * 256 + tid) >> 6;
    float4 bi = rois[node];
    unsigned long long myword = 0;
    int mn = node;
    for (int w = 0; w < 64; ++w) {
      int j = w * 64 + lane;
      float4 bj = rois[j];
      float iw = fminf(bi.z, bj.z) - fmaxf(bi.x, bj.x) + 1.0f;
      float ih = fminf(bi.w, bj.w) - fmaxf(bi.y, bj.y) + 1.0f;
      bool ov = (iw > 0.f) && (ih > 0.f) && (j != node);
      unsigned long long msk = __ballot(ov);
      if (lane == w) myword = msk;
      if (msk) mn = min(mn, w * 64 + (int)__builtin_ctzll(msk));
    }
    adj[(size_t)node * 64 + lane] = myword;
    if (lane == 0) labels[node] = mn;
  }
}

// merged prep: [0,4096) XRT transpose (Xb*rinorm), [4096,4608) Wg1T,
//              [4608,4864) Wg2T, [4864,5120) WcatT
__global__ void k_prep(const __hip_bfloat16* __restrict__ Xb, const float* __restrict__ rinorm,
                       const float* __restrict__ Wg1, const float* __restrict__ Wg2,
                       const float* __restrict__ Wb, const float* __restrict__ Wc,
                       __hip_bfloat16* __restrict__ XRT, __hip_bfloat16* __restrict__ Wg1T,
                       __hip_bfloat16* __restrict__ Wg2T, __hip_bfloat16* __restrict__ WcatT) {
  __shared__ float s[32][33];
  const int tid = threadIdx.x;
  const int tx = tid & 31, ty = tid >> 5;  // (32,8)
  int blk = blockIdx.x;
  if (blk < 4096) {
    int c0 = (blk & 31) * 32, r0 = (blk >> 5) * 32;
#pragma unroll
    for (int k = 0; k < 4; ++k) {
      int r = r0 + ty + k * 8;
      s[ty + k * 8][tx] = __bfloat162float(Xb[(size_t)r * 1024 + c0 + tx]) * rinorm[r];
    }
    __syncthreads();
#pragma unroll
    for (int k = 0; k < 4; ++k)
      XRT[(size_t)(c0 + ty + k * 8) * 4096 + r0 + tx] = __float2bfloat16(s[tx][ty + k * 8]);
  } else if (blk < 4608) {
    int l = blk - 4096;
    int c0 = (l & 15) * 32, r0 = (l >> 4) * 32;
#pragma unroll
    for (int k = 0; k < 4; ++k)
      s[ty + k * 8][tx] = Wg1[(size_t)(r0 + ty + k * 8) * 512 + c0 + tx];
    __syncthreads();
#pragma unroll
    for (int k = 0; k < 4; ++k)
      Wg1T[(size_t)(c0 + ty + k * 8) * 1024 + r0 + tx] = __float2bfloat16(s[tx][ty + k * 8]);
  } else if (blk < 4864) {
    int l = blk - 4608;
    int c0 = (l & 15) * 32, r0 = (l >> 4) * 32;
#pragma unroll
    for (int k = 0; k < 4; ++k)
      s[ty + k * 8][tx] = Wg2[(size_t)(r0 + ty + k * 8) * 512 + c0 + tx];
    __syncthreads();
#pragma unroll
    for (int k = 0; k < 4; ++k)
      Wg2T[(size_t)(c0 + ty + k * 8) * 512 + r0 + tx] = __float2bfloat16(s[tx][ty + k * 8]);
  } else {
    int idx = (blk - 4864) * 256 + tid;
    int r = idx >> 9, k = idx & 511;
    float v = 0.f;
    if (r < 84) v = Wb[(size_t)k * 84 + r];
    else if (r < 105) v = Wc[(size_t)k * 21 + (r - 84)];
    WcatT[idx] = __float2bfloat16(v);
  }
}

// ---------------- connected components ----------------
__global__ void k_minprop(const unsigned long long* __restrict__ adj, int* __restrict__ labels) {
  int wave = (blockIdx.x * 256 + threadIdx.x) >> 6;
  int lane = threadIdx.x & 63;
  unsigned long long w = adj[(size_t)wave * 64 + lane];
  int m = 0x7fffffff;
  while (w) {
    int b = __builtin_ctzll(w);
    w &= w - 1;
    m = min(m, labels[lane * 64 + b]);
  }
  for (int o = 32; o; o >>= 1) m = min(m, __shfl_down(m, o));
  if (lane == 0 && m < labels[wave]) atomicMin(&labels[wave], m);
}

__global__ void k_jump(int* __restrict__ labels, float* __restrict__ outL) {
  __shared__ int a[4096];
  __shared__ int b[4096];
  int t = threadIdx.x;
  for (int i = t; i < 4096; i += 1024) a[i] = labels[i];
  __syncthreads();
  int* src = a;
  int* dst = b;
  for (int it = 0; it < 12; ++it) {  // 2^12 >= 4096
    for (int i = t; i < 4096; i += 1024) dst[i] = src[src[i]];
    __syncthreads();
    int* tp = src; src = dst; dst = tp;
  }
  for (int i = t; i < 4096; i += 1024) outL[i] = (float)src[i];
}

// ---------------- launch ----------------
extern "C" void kernel_launch(void* const* d_in, const int* in_sizes, int n_in,
                              void* d_out, int out_size, void* d_ws, size_t ws_size,
                              hipStream_t stream) {
  const float* rois = (const float*)d_in[0];
  const float* X    = (const float*)d_in[1];
  const float* Wg1  = (const float*)d_in[2];
  const float* bg1  = (const float*)d_in[3];
  const float* Wg2  = (const float*)d_in[4];
  const float* bg2  = (const float*)d_in[5];
  const float* Wb   = (const float*)d_in[6];
  const float* bb   = (const float*)d_in[7];
  const float* Wc   = (const float*)d_in[8];
  const float* bc   = (const float*)d_in[9];

  float* out        = (float*)d_out;
  float* out_labels = out;
  float* out_cls    = out + 4096;
  float* out_bbox   = out + 4096 + 4096 * 21;

  char* p = (char*)d_ws;
  auto carve = [&](size_t bytes) { char* r = p; p += (bytes + 255) & ~(size_t)255; return r; };
  int* labels           = (int*)carve(4096ull * 4);
  float* rinorm         = (float*)carve(4096ull * 4);
  __hip_bfloat16* WcatT = (__hip_bfloat16*)carve(128ull * 512 * 2);
  __hip_bfloat16* Wg2T  = (__hip_bfloat16*)carve(512ull * 512 * 2);
  __hip_bfloat16* Wg1T  = (__hip_bfloat16*)carve(512ull * 1024 * 2);
  __hip_bfloat16* T2T   = (__hip_bfloat16*)carve(512ull * 1024 * 2);
  __hip_bfloat16* h     = (__hip_bfloat16*)carve(4096ull * 512 * 2);
  __hip_bfloat16* ST    = (__hip_bfloat16*)carve(512ull * 4096 * 2);
  __hip_bfloat16* Xb    = (__hip_bfloat16*)carve(4096ull * 1024 * 2);
  __hip_bfloat16* XRT   = (__hip_bfloat16*)carve(1024ull * 4096 * 2);
  unsigned long long* adj = (unsigned long long*)carve(4096ull * 64 * 8);
  float* part           = (float*)carve(16ull * 1024 * 1024);

  // D1: nf + adj(+hook0)
  k_nf_adj<<<2048, 256, 0, stream>>>(X, Xb, rinorm, (const float4*)rois, adj, labels);
  // D2: prep (transposes + Wcat)
  k_prep<<<5120, 256, 0, stream>>>(Xb, rinorm, Wg1, Wg2, Wb, Wc, XRT, Wg1T, Wg2T, WcatT);
  // CC: 2 atomic hooks, final compress
  for (int r = 0; r < 2; ++r) k_minprop<<<1024, 256, 0, stream>>>(adj, labels);
  k_jump<<<1, 1024, 0, stream>>>(labels, out_labels);

  // ---- layer 1 ----
  gemm64<1><<<dim3(64, 8), 256, 0, stream>>>(Wg1T, Xb, 1024, 1024, 4096, part,
                                             nullptr, nullptr, nullptr, ST,
                                             nullptr, nullptr, nullptr);
  gemm64<0><<<dim3(16, 8, 4), 256, 0, stream>>>(ST, XRT, 1024, 4096, 1024, part,
                                                nullptr, nullptr, nullptr, nullptr,
                                                nullptr, nullptr, nullptr);
  k_red0<<<512, 256, 0, stream>>>(part, T2T, 512 * 1024, 4);
  gemm64<2><<<dim3(8, 64), 256, 0, stream>>>(Xb, T2T, 1024, 1024, 512, part,
                                             rinorm, ST, bg1, h,
                                             nullptr, nullptr, nullptr);
  // ---- layer 2 ----
  gemm64<1><<<dim3(64, 8), 256, 0, stream>>>(Wg2T, h, 512, 512, 4096, part,
                                             nullptr, nullptr, nullptr, ST,
                                             nullptr, nullptr, nullptr);
  gemm64<0><<<dim3(16, 8, 4), 256, 0, stream>>>(ST, XRT, 1024, 4096, 1024, part,
                                                nullptr, nullptr, nullptr, nullptr,
                                                nullptr, nullptr, nullptr);
  k_red0<<<512, 256, 0, stream>>>(part, T2T, 512 * 1024, 4);
  gemm64<2><<<dim3(8, 64), 256, 0, stream>>>(Xb, T2T, 1024, 1024, 512, part,
                                             rinorm, ST, bg2, h,
                                             nullptr, nullptr, nullptr);
  // ---- heads: unsplit K=512, direct bbox + fused softmax ----
  gemm64<3><<<dim3(2, 64), 256, 0, stream>>>(h, WcatT, 512, 512, 128, part,
                                             nullptr, nullptr, bb, nullptr,
                                             out_bbox, out_cls, bc);
}